// Round 1
// baseline (1364.731 us; speedup 1.0000x reference)
//
#include <hip/hip_runtime.h>
#include <math.h>

#define BDIM 16
#define LDIM 512
#define CDIM 1024
#define NH 8
#define HD 128
#define MROWS (BDIM * LDIM)   /* 8192 */
#define N3 (3 * CDIM)         /* 3072 */

__device__ __forceinline__ float sigmoidf_(float z) {
    return 1.0f / (1.0f + __expf(-z));
}

// ---------------- Kernel 1: degree = adj.sum(-1) ----------------
__global__ void degree_kernel(const float* __restrict__ adj, float* __restrict__ deg) {
    int row = blockIdx.x;            // 0..B*L-1
    int lane = threadIdx.x;          // 0..63
    const float* a = adj + (size_t)row * LDIM;
    float s = 0.f;
    #pragma unroll
    for (int m = 0; m < LDIM; m += 64) s += a[m + lane];
    #pragma unroll
    for (int off = 32; off > 0; off >>= 1) s += __shfl_down(s, off);
    if (lane == 0) deg[row] = s;
}

// ---------------- Kernel 2: xg = x * sigmoid(deg*W_d + b_d) ----------------
__global__ void gate_kernel(const float* __restrict__ x, const float* __restrict__ deg,
                            const float* __restrict__ Wd, const float* __restrict__ bd,
                            float* __restrict__ xg) {
    int row = blockIdx.x;            // b*L + l
    int t = threadIdx.x;             // 256 threads -> 256 float4 = 1024 floats
    float d = deg[row];
    float4 xv = ((const float4*)(x + (size_t)row * CDIM))[t];
    float4 wv = ((const float4*)Wd)[t];
    float4 bv = ((const float4*)bd)[t];
    float4 o;
    o.x = xv.x * sigmoidf_(d * wv.x + bv.x);
    o.y = xv.y * sigmoidf_(d * wv.y + bv.y);
    o.z = xv.z * sigmoidf_(d * wv.z + bv.z);
    o.w = xv.w * sigmoidf_(d * wv.w + bv.w);
    ((float4*)(xg + (size_t)row * CDIM))[t] = o;
}

// ---------------- Kernel 3: qkv = xg @ W_qkv + b_qkv ----------------
// M=8192, N=3072, K=1024, fp32. 128x128 block tile, 8x8 microtile, BK=16.
#define BM 128
#define BN 128
#define BK 16

__global__ __launch_bounds__(256) void gemm_kernel(const float* __restrict__ A,
                                                   const float* __restrict__ Bm,
                                                   const float* __restrict__ bias,
                                                   float* __restrict__ Cm) {
    __shared__ float As[BK][BM];   // transposed A tile: As[k][m]
    __shared__ float Bs[BK][BN];   // Bs[k][n]
    int t = threadIdx.x;
    int m0 = blockIdx.y * BM;
    int n0 = blockIdx.x * BN;
    int tm = t >> 4;               // 0..15
    int tn = t & 15;               // 0..15

    int ar = t >> 2;               // 0..63
    int ac = (t & 3) * 4;          // 0,4,8,12
    int br = t >> 5;               // 0..7
    int bc = (t & 31) * 4;         // 0..124

    float acc[8][8];
    #pragma unroll
    for (int i = 0; i < 8; ++i)
        #pragma unroll
        for (int j = 0; j < 8; ++j) acc[i][j] = 0.f;

    for (int k0 = 0; k0 < CDIM; k0 += BK) {
        #pragma unroll
        for (int p = 0; p < 2; ++p) {
            int mrow = ar + p * 64;
            float4 av = *(const float4*)(A + (size_t)(m0 + mrow) * CDIM + k0 + ac);
            As[ac + 0][mrow] = av.x;
            As[ac + 1][mrow] = av.y;
            As[ac + 2][mrow] = av.z;
            As[ac + 3][mrow] = av.w;
        }
        #pragma unroll
        for (int p = 0; p < 2; ++p) {
            int krow = br + p * 8;
            float4 bv = *(const float4*)(Bm + (size_t)(k0 + krow) * N3 + n0 + bc);
            *(float4*)(&Bs[krow][bc]) = bv;
        }
        __syncthreads();
        #pragma unroll
        for (int kk = 0; kk < BK; ++kk) {
            float ra[8], rb[8];
            *(float4*)&ra[0] = *(const float4*)&As[kk][tm * 8];
            *(float4*)&ra[4] = *(const float4*)&As[kk][tm * 8 + 4];
            *(float4*)&rb[0] = *(const float4*)&Bs[kk][tn * 8];
            *(float4*)&rb[4] = *(const float4*)&Bs[kk][tn * 8 + 4];
            #pragma unroll
            for (int i = 0; i < 8; ++i)
                #pragma unroll
                for (int j = 0; j < 8; ++j)
                    acc[i][j] += ra[i] * rb[j];
        }
        __syncthreads();
    }

    #pragma unroll
    for (int i = 0; i < 8; ++i) {
        int m = m0 + tm * 8 + i;
        float* crow = Cm + (size_t)m * N3 + n0 + tn * 8;
        const float* brow = bias + n0 + tn * 8;
        #pragma unroll
        for (int j = 0; j < 8; j += 4) {
            float4 v;
            v.x = acc[i][j + 0] + brow[j + 0];
            v.y = acc[i][j + 1] + brow[j + 1];
            v.z = acc[i][j + 2] + brow[j + 2];
            v.w = acc[i][j + 3] + brow[j + 3];
            *(float4*)(crow + j) = v;
        }
    }
}

// ---------------- Kernel 4: fused sigmoid-kernel attention ----------------
// Per block: (b, h, 16 l-rows). Loop m in tiles of 32.
// S = sig(qk_l) . sig(qk_m)^T / sqrt(HD), masked by adj; accumulate S.V and
// rowsum; final out = S.V/(rowsum+1e-6) + res, relu. (Linear normalization:
// no online rescaling needed.)
#define LT 16
#define MT 32
#define KPAD 132   // 128 + 4 words: breaks the stride-128 (16-way) bank conflict

__global__ __launch_bounds__(256) void attn_kernel(const float* __restrict__ qkv,
                                                   const float* __restrict__ adj,
                                                   float* __restrict__ out) {
    __shared__ float Qs[LT][HD];      // 8 KB  (sigmoid applied)
    __shared__ float Ks[MT][KPAD];    // 16.5 KB (sigmoid applied)
    __shared__ float Vs[MT][HD];      // 16 KB
    __shared__ float Ss[LT][MT];      // 2 KB (masked, scaled scores)
    __shared__ float rowsum[LT];

    int t = threadIdx.x;              // 256
    int l0 = blockIdx.x * LT;
    int h  = blockIdx.y;
    int b  = blockIdx.z;
    const float* qkvb = qkv + (size_t)b * LDIM * N3;

    // stage Q tile with sigmoid: 16 x 128 = 512 float4
    for (int i = t; i < LT * HD / 4; i += 256) {
        int row = i >> 5, c4 = (i & 31) * 4;
        float4 v = *(const float4*)(qkvb + (size_t)(l0 + row) * N3 + h * HD + c4);
        float4 s;
        s.x = sigmoidf_(v.x); s.y = sigmoidf_(v.y);
        s.z = sigmoidf_(v.z); s.w = sigmoidf_(v.w);
        *(float4*)&Qs[row][c4] = s;
    }
    if (t < LT) rowsum[t] = 0.f;

    int li = t >> 4;                  // out row owned by this thread
    int d0 = (t & 15) * 8;            // out d-chunk owned by this thread
    float acc[8];
    #pragma unroll
    for (int j = 0; j < 8; ++j) acc[j] = 0.f;

    __syncthreads();

    const float scale = 0.08838834764831845f;  // 1/sqrt(128)

    for (int m0 = 0; m0 < LDIM; m0 += MT) {
        // stage K (sigmoid) and V tiles: 32 x 128 each = 1024 float4 each
        for (int i = t; i < MT * HD / 4; i += 256) {
            int row = i >> 5, c4 = (i & 31) * 4;
            const float* rp = qkvb + (size_t)(m0 + row) * N3;
            float4 kv = *(const float4*)(rp + h * HD + c4);            // qk chunk
            float4 vv = *(const float4*)(rp + 2 * CDIM + h * HD + c4); // value chunk
            float4 ks;
            ks.x = sigmoidf_(kv.x); ks.y = sigmoidf_(kv.y);
            ks.z = sigmoidf_(kv.z); ks.w = sigmoidf_(kv.w);
            *(float4*)&Ks[row][c4] = ks;
            *(float4*)&Vs[row][c4] = vv;
        }
        __syncthreads();

        // scores: thread (sl = t>>4, mb = t&15) computes m = mb, mb+16
        {
            int sl = t >> 4;
            int mb = t & 15;
            float sacc[2] = {0.f, 0.f};
            #pragma unroll 8
            for (int d = 0; d < HD; d += 4) {
                float4 q = *(const float4*)&Qs[sl][d];
                #pragma unroll
                for (int j = 0; j < 2; ++j) {
                    float4 kv = *(const float4*)&Ks[mb + 16 * j][d];
                    sacc[j] += q.x * kv.x + q.y * kv.y + q.z * kv.z + q.w * kv.w;
                }
            }
            float rs = 0.f;
            #pragma unroll
            for (int j = 0; j < 2; ++j) {
                int m = m0 + mb + 16 * j;
                float a = adj[((size_t)b * LDIM + (l0 + sl)) * LDIM + m];
                float sv = (a != 0.f) ? sacc[j] * scale : 0.f;
                Ss[sl][mb + 16 * j] = sv;
                rs += sv;
            }
            atomicAdd(&rowsum[sl], rs);
        }
        __syncthreads();

        // PV: acc[j] += sum_m Ss[li][m] * Vs[m][d0+j]
        #pragma unroll 4
        for (int m = 0; m < MT; ++m) {
            float s = Ss[li][m];
            const float* vp = &Vs[m][d0];
            #pragma unroll
            for (int j = 0; j < 8; ++j) acc[j] += s * vp[j];
        }
        __syncthreads();
    }

    float rs = rowsum[li] + 1e-6f;
    float inv = 1.0f / rs;
    const float* resp = qkvb + (size_t)(l0 + li) * N3 + CDIM + h * HD + d0;
    float* op = out + ((size_t)b * LDIM + (l0 + li)) * CDIM + h * HD + d0;
    #pragma unroll
    for (int j = 0; j < 8; ++j) {
        float v = acc[j] * inv + resp[j];
        op[j] = fmaxf(v, 0.f);
    }
}

// ---------------- launch ----------------
extern "C" void kernel_launch(void* const* d_in, const int* in_sizes, int n_in,
                              void* d_out, int out_size, void* d_ws, size_t ws_size,
                              hipStream_t stream) {
    (void)in_sizes; (void)n_in; (void)out_size; (void)ws_size;
    const float* x     = (const float*)d_in[0];
    const float* adj   = (const float*)d_in[1];
    const float* W_qkv = (const float*)d_in[2];
    const float* b_qkv = (const float*)d_in[3];
    const float* W_d   = (const float*)d_in[4];
    const float* b_d   = (const float*)d_in[5];
    float* out = (float*)d_out;

    char* ws = (char*)d_ws;
    float* deg = (float*)ws;                                   // 8192 floats
    float* xg  = (float*)(ws + 65536);                         // 8192*1024 fp32 = 32 MB
    float* qkv = (float*)(ws + 65536 + (size_t)MROWS * CDIM * 4); // 8192*3072 fp32 = 96 MB

    degree_kernel<<<MROWS, 64, 0, stream>>>(adj, deg);
    gate_kernel<<<MROWS, 256, 0, stream>>>(x, deg, W_d, b_d, xg);
    gemm_kernel<<<dim3(N3 / BN, MROWS / BM), 256, 0, stream>>>(xg, W_qkv, b_qkv, qkv);
    attn_kernel<<<dim3(LDIM / LT, NH, BDIM), 256, 0, stream>>>(qkv, adj, out);
}

// Round 2
// 345.855 us; speedup vs baseline: 3.9460x; 3.9460x over previous
//
#include <hip/hip_runtime.h>
#include <math.h>

#define BDIM 16
#define LDIM 512
#define CDIM 1024
#define NH 8
#define HD 128
#define MROWS (BDIM * LDIM)   /* 8192 */
#define N3 (3 * CDIM)         /* 3072 */

typedef unsigned short u16;
typedef short s8v __attribute__((ext_vector_type(8)));   // 8 bf16 = 4 VGPRs (MFMA A/B frag)
typedef short s4v __attribute__((ext_vector_type(4)));   // 4 bf16 = 2 VGPRs
typedef float f32x4 __attribute__((ext_vector_type(4))); // MFMA C/D frag

__device__ __forceinline__ float sigmoidf_(float z) {
    return 1.0f / (1.0f + __expf(-z));
}
__device__ __forceinline__ u16 f2bf(float f) {
    union { float f; unsigned int u; } v; v.f = f;
    unsigned int u = v.u;
    unsigned int r = (u + 0x7FFFu + ((u >> 16) & 1u)) >> 16;   // round-nearest-even
    return (u16)r;
}

// ---------------- Kernel 1: degree = adj.sum(-1) ----------------
__global__ void degree_kernel(const float* __restrict__ adj, float* __restrict__ deg) {
    int row = blockIdx.x;
    int lane = threadIdx.x;
    const float* a = adj + (size_t)row * LDIM;
    float s = 0.f;
    #pragma unroll
    for (int m = 0; m < LDIM; m += 64) s += a[m + lane];
    #pragma unroll
    for (int off = 32; off > 0; off >>= 1) s += __shfl_down(s, off);
    if (lane == 0) deg[row] = s;
}

// ---------------- Kernel 2: xg = bf16( x * sigmoid(deg*W_d + b_d) ) ----------------
__global__ void gate_kernel(const float* __restrict__ x, const float* __restrict__ deg,
                            const float* __restrict__ Wd, const float* __restrict__ bd,
                            u16* __restrict__ xg) {
    int row = blockIdx.x;
    int t = threadIdx.x;
    float d = deg[row];
    float4 xv = ((const float4*)(x + (size_t)row * CDIM))[t];
    float4 wv = ((const float4*)Wd)[t];
    float4 bv = ((const float4*)bd)[t];
    s4v o;
    o.x = (short)f2bf(xv.x * sigmoidf_(d * wv.x + bv.x));
    o.y = (short)f2bf(xv.y * sigmoidf_(d * wv.y + bv.y));
    o.z = (short)f2bf(xv.z * sigmoidf_(d * wv.z + bv.z));
    o.w = (short)f2bf(xv.w * sigmoidf_(d * wv.w + bv.w));
    ((s4v*)(xg + (size_t)row * CDIM))[t] = o;
}

// ---------------- Kernel 3: Wt[n][k] = bf16(W[k][n]) (transpose 1024x3072) -----------
__global__ void packW_kernel(const float* __restrict__ W, u16* __restrict__ Wt) {
    __shared__ float tile[64][65];
    int k0 = blockIdx.x * 64, n0 = blockIdx.y * 64;
    int tx = threadIdx.x & 63, ty = threadIdx.x >> 6;  // ty 0..3
    #pragma unroll
    for (int yy = ty; yy < 64; yy += 4)
        tile[yy][tx] = W[(size_t)(k0 + yy) * N3 + n0 + tx];
    __syncthreads();
    #pragma unroll
    for (int yy = ty; yy < 64; yy += 4)
        Wt[(size_t)(n0 + yy) * CDIM + k0 + tx] = f2bf(tile[tx][yy]);
}

// ---------------- Kernel 4: bf16 MFMA GEMM, fused chunk epilogue ----------------
// qkv = xg @ W + b : M=8192, N=3072, K=1024. A=[M][K] bf16, Bt=[N][K] bf16.
// chunk 0 (qk):  sigmoid -> Ksig bf16 [B,H,L,HD]
// chunk 1 (res): fp32 [B,L,C]
// chunk 2 (val): fp32 [B,L,C]
__global__ __launch_bounds__(256) void gemm_bf16_kernel(const u16* __restrict__ A,
                                                        const u16* __restrict__ Bt,
                                                        const float* __restrict__ bias,
                                                        u16* __restrict__ ksig,
                                                        float* __restrict__ resb,
                                                        float* __restrict__ vv) {
    __shared__ __align__(16) u16 As[128][72];   // 64 bf16 + 8 pad
    __shared__ __align__(16) u16 Bs[128][72];
    int t = threadIdx.x;
    int m0 = blockIdx.y * 128, n0 = blockIdx.x * 128;
    int lane = t & 63, w = t >> 6;
    int i15 = lane & 15, quad = lane >> 4;
    int wm = w >> 1, wn = w & 1;

    f32x4 acc[4][4];
    #pragma unroll
    for (int i = 0; i < 4; ++i)
        #pragma unroll
        for (int j = 0; j < 4; ++j) acc[i][j] = (f32x4)(0.f);

    int srow = t >> 3, sc8 = t & 7;   // 32 rows/pass, 8x16B per row

    for (int k0 = 0; k0 < CDIM; k0 += 64) {
        #pragma unroll
        for (int p = 0; p < 4; ++p) {
            int row = srow + p * 32;
            *(s8v*)&As[row][sc8 * 8] = *(const s8v*)(A + (size_t)(m0 + row) * CDIM + k0 + sc8 * 8);
            *(s8v*)&Bs[row][sc8 * 8] = *(const s8v*)(Bt + (size_t)(n0 + row) * CDIM + k0 + sc8 * 8);
        }
        __syncthreads();
        #pragma unroll
        for (int kc = 0; kc < 2; ++kc) {
            s8v aF[4], bF[4];
            #pragma unroll
            for (int mt = 0; mt < 4; ++mt)
                aF[mt] = *(const s8v*)&As[wm * 64 + mt * 16 + i15][kc * 32 + quad * 8];
            #pragma unroll
            for (int nt = 0; nt < 4; ++nt)
                bF[nt] = *(const s8v*)&Bs[wn * 64 + nt * 16 + i15][kc * 32 + quad * 8];
            #pragma unroll
            for (int mt = 0; mt < 4; ++mt)
                #pragma unroll
                for (int nt = 0; nt < 4; ++nt)
                    acc[mt][nt] = __builtin_amdgcn_mfma_f32_16x16x32_bf16(aF[mt], bF[nt], acc[mt][nt], 0, 0, 0);
        }
        __syncthreads();
    }

    int chunk = n0 >> 10;
    #pragma unroll
    for (int nt = 0; nt < 4; ++nt) {
        int ncol = n0 + wn * 64 + nt * 16 + i15;
        float bv = bias[ncol];
        #pragma unroll
        for (int mt = 0; mt < 4; ++mt) {
            int mbase = m0 + wm * 64 + mt * 16 + quad * 4;
            #pragma unroll
            for (int r = 0; r < 4; ++r) {
                int mrow = mbase + r;
                float v = acc[mt][nt][r] + bv;
                if (chunk == 0) {
                    int h = ncol >> 7, d = ncol & 127;
                    int bb = mrow >> 9, l = mrow & 511;
                    ksig[(((size_t)bb * NH + h) * LDIM + l) * HD + d] = f2bf(sigmoidf_(v));
                } else if (chunk == 1) {
                    resb[(size_t)mrow * CDIM + (ncol - CDIM)] = v;
                } else {
                    vv[(size_t)mrow * CDIM + (ncol - 2 * CDIM)] = v;
                }
            }
        }
    }
}

// ---------------- Kernel 5: fused MFMA attention ----------------
// Per block: (b, h, 64 l-rows), 4 waves x 16 rows. m-tiles of 64 keys.
// O_unnorm += P.V, rowsum += sum(P); divide once at the end (linear norm).
__global__ __launch_bounds__(256) void attn_kernel(const u16* __restrict__ ksig,
                                                   const float* __restrict__ vv,
                                                   const float* __restrict__ resb,
                                                   const float* __restrict__ adj,
                                                   float* __restrict__ out) {
    __shared__ __align__(16) u16 lds_ks[64][144];  // 128 bf16 + 16 pad -> b128 frag reads at bank floor
    __shared__ __align__(16) u16 lds_vt[128][68];  // V^T: [d][m], 64 + 4 pad -> b64 frags, b32 cf writes
    __shared__ __align__(16) u16 lds_ps[4][16][72];// per-wave P tile [l][m], 64 + 8 pad

    int t = threadIdx.x;
    int lane = t & 63, w = t >> 6;
    int i15 = lane & 15, quad = lane >> 4;
    int l0 = blockIdx.x * 64;
    int h  = blockIdx.y;
    int b  = blockIdx.z;

    const u16* ksig_bh = ksig + ((size_t)b * NH + h) * LDIM * HD;

    // Q A-frags from global (sigmoid pre-applied in GEMM epilogue)
    s8v aQ[4];
    {
        const u16* qrow = ksig_bh + (size_t)(l0 + w * 16 + i15) * HD + quad * 8;
        #pragma unroll
        for (int kc = 0; kc < 4; ++kc) aQ[kc] = *(const s8v*)(qrow + kc * 32);
    }

    f32x4 accO[8];
    #pragma unroll
    for (int i = 0; i < 8; ++i) accO[i] = (f32x4)(0.f);
    float prs[4] = {0.f, 0.f, 0.f, 0.f};

    const float scale = 0.08838834764831845f;  // 1/sqrt(128)
    int vd = t & 127;                          // Vt staging: this thread's d
    int vmh = t >> 7;                          // 0/1: pair-row parity

    for (int m0 = 0; m0 < LDIM; m0 += 64) {
        // --- stage K tile (bf16 copy, padded rows) ---
        #pragma unroll
        for (int p = 0; p < 4; ++p) {
            int c = t + p * 256;
            int row = c >> 4, c16 = c & 15;
            *(s8v*)&lds_ks[row][c16 * 8] =
                *(const s8v*)(ksig_bh + (size_t)(m0 + row) * HD + c16 * 8);
        }
        // --- stage V tile transposed: Vt[d][m] bf16, packed-pair b32 writes ---
        {
            const float* vbase = vv + ((size_t)b * LDIM + m0) * CDIM + h * HD + vd;
            #pragma unroll
            for (int mp = 0; mp < 16; ++mp) {
                int pr = vmh + 2 * mp;         // pair index 0..31
                float v0 = vbase[(size_t)(2 * pr) * CDIM];
                float v1 = vbase[(size_t)(2 * pr + 1) * CDIM];
                unsigned int pk = (unsigned int)f2bf(v0) | ((unsigned int)f2bf(v1) << 16);
                *(unsigned int*)&lds_vt[vd][2 * pr] = pk;
            }
        }
        __syncthreads();

        // --- S = sig(Q) sig(K)^T : 4 key-tiles x 4 k-steps ---
        f32x4 S[4];
        #pragma unroll
        for (int nt = 0; nt < 4; ++nt) {
            S[nt] = (f32x4)(0.f);
            #pragma unroll
            for (int kc = 0; kc < 4; ++kc) {
                s8v bK = *(const s8v*)&lds_ks[nt * 16 + i15][kc * 32 + quad * 8];
                S[nt] = __builtin_amdgcn_mfma_f32_16x16x32_bf16(aQ[kc], bK, S[nt], 0, 0, 0);
            }
        }

        // --- mask (multiply by adj 0/1), rowsum, P -> LDS (per-wave, no barrier) ---
        {
            size_t abase = ((size_t)b * LDIM + l0 + w * 16) * LDIM + m0;
            #pragma unroll
            for (int nt = 0; nt < 4; ++nt) {
                int mg = nt * 16 + i15;
                #pragma unroll
                for (int r = 0; r < 4; ++r) {
                    float a = adj[abase + (size_t)(quad * 4 + r) * LDIM + mg];
                    float p = S[nt][r] * scale * a;
                    prs[r] += p;
                    lds_ps[w][quad * 4 + r][nt * 16 + i15] = f2bf(p);
                }
            }
        }

        // --- O += P . V ---
        {
            s8v aP[2];
            #pragma unroll
            for (int ks = 0; ks < 2; ++ks)
                aP[ks] = *(const s8v*)&lds_ps[w][i15][ks * 32 + quad * 8];
            #pragma unroll
            for (int ntd = 0; ntd < 8; ++ntd) {
                #pragma unroll
                for (int ks = 0; ks < 2; ++ks) {
                    const u16* vp = &lds_vt[ntd * 16 + i15][ks * 32 + quad * 8];
                    s4v lo = *(const s4v*)vp;
                    s4v hi = *(const s4v*)(vp + 4);
                    s8v bV = __builtin_shufflevector(lo, hi, 0, 1, 2, 3, 4, 5, 6, 7);
                    accO[ntd] = __builtin_amdgcn_mfma_f32_16x16x32_bf16(aP[ks], bV, accO[ntd], 0, 0, 0);
                }
            }
        }
        __syncthreads();
    }

    // --- epilogue: reduce rowsums across the 16 key-lanes, normalize, +res, relu ---
    float inv[4];
    #pragma unroll
    for (int r = 0; r < 4; ++r) {
        float s = prs[r];
        s += __shfl_xor(s, 1);
        s += __shfl_xor(s, 2);
        s += __shfl_xor(s, 4);
        s += __shfl_xor(s, 8);
        inv[r] = 1.0f / (s + 1e-6f);
    }
    #pragma unroll
    for (int ntd = 0; ntd < 8; ++ntd) {
        int dcol = h * HD + ntd * 16 + i15;
        #pragma unroll
        for (int r = 0; r < 4; ++r) {
            size_t idx = ((size_t)b * LDIM + l0 + w * 16 + quad * 4 + r) * CDIM + dcol;
            float v = accO[ntd][r] * inv[r] + resb[idx];
            out[idx] = fmaxf(v, 0.f);
        }
    }
}

// ---------------- launch ----------------
extern "C" void kernel_launch(void* const* d_in, const int* in_sizes, int n_in,
                              void* d_out, int out_size, void* d_ws, size_t ws_size,
                              hipStream_t stream) {
    (void)in_sizes; (void)n_in; (void)out_size; (void)ws_size;
    const float* x     = (const float*)d_in[0];
    const float* adj   = (const float*)d_in[1];
    const float* W_qkv = (const float*)d_in[2];
    const float* b_qkv = (const float*)d_in[3];
    const float* W_d   = (const float*)d_in[4];
    const float* b_d   = (const float*)d_in[5];
    float* out = (float*)d_out;

    char* ws = (char*)d_ws;
    size_t off = 0;
    float* deg  = (float*)(ws + off); off += 32768;                       // 8192 f32
    u16*   xg   = (u16*)(ws + off);   off += (size_t)MROWS * CDIM * 2;    // 16 MB
    u16*   Wt   = (u16*)(ws + off);   off += (size_t)N3 * CDIM * 2;       // 6 MB
    u16*   ksig = (u16*)(ws + off);   off += (size_t)MROWS * CDIM * 2;    // 16 MB
    float* resb = (float*)(ws + off); off += (size_t)MROWS * CDIM * 4;    // 32 MB
    float* vv   = (float*)(ws + off); off += (size_t)MROWS * CDIM * 4;    // 32 MB

    degree_kernel<<<MROWS, 64, 0, stream>>>(adj, deg);
    gate_kernel<<<MROWS, 256, 0, stream>>>(x, deg, W_d, b_d, xg);
    packW_kernel<<<dim3(CDIM / 64, N3 / 64), 256, 0, stream>>>(W_qkv, Wt);
    gemm_bf16_kernel<<<dim3(N3 / 128, MROWS / 128), 256, 0, stream>>>(xg, Wt, b_qkv, ksig, resb, vv);
    attn_kernel<<<dim3(LDIM / 64, NH, BDIM), 256, 0, stream>>>(ksig, vv, resb, adj, out);
}

// Round 3
// 277.315 us; speedup vs baseline: 4.9212x; 1.2472x over previous
//
#include <hip/hip_runtime.h>
#include <math.h>

#define BDIM 16
#define LDIM 512
#define CDIM 1024
#define NH 8
#define HD 128
#define MROWS (BDIM * LDIM)   /* 8192 */
#define N3 (3 * CDIM)         /* 3072 */

typedef unsigned short u16;
typedef short s8v __attribute__((ext_vector_type(8)));   // 8 bf16 = 4 VGPRs (MFMA A/B frag)
typedef short s4v __attribute__((ext_vector_type(4)));   // 4 bf16 = 2 VGPRs
typedef float f32x4 __attribute__((ext_vector_type(4))); // MFMA C/D frag

__device__ __forceinline__ float sigmoidf_(float z) {
    return 1.0f / (1.0f + __expf(-z));
}
__device__ __forceinline__ u16 f2bf(float f) {
    union { float f; unsigned int u; } v; v.f = f;
    unsigned int u = v.u;
    unsigned int r = (u + 0x7FFFu + ((u >> 16) & 1u)) >> 16;   // round-nearest-even
    return (u16)r;
}
__device__ __forceinline__ float andmaskf_(float s, int m) {
    union { float f; unsigned int u; } v; v.f = s;
    v.u &= (unsigned int)m;
    return v.f;
}

// ---------------- Kernel 1: degree = adj.sum(-1) ----------------
__global__ void degree_kernel(const float* __restrict__ adj, float* __restrict__ deg) {
    int row = blockIdx.x;
    int lane = threadIdx.x;
    const float* a = adj + (size_t)row * LDIM;
    float s = 0.f;
    #pragma unroll
    for (int m = 0; m < LDIM; m += 64) s += a[m + lane];
    #pragma unroll
    for (int off = 32; off > 0; off >>= 1) s += __shfl_down(s, off);
    if (lane == 0) deg[row] = s;
}

// ---------------- Kernel 2: xg = bf16( x * sigmoid(deg*W_d + b_d) ) ----------------
__global__ void gate_kernel(const float* __restrict__ x, const float* __restrict__ deg,
                            const float* __restrict__ Wd, const float* __restrict__ bd,
                            u16* __restrict__ xg) {
    int row = blockIdx.x;
    int t = threadIdx.x;
    float d = deg[row];
    float4 xv = ((const float4*)(x + (size_t)row * CDIM))[t];
    float4 wv = ((const float4*)Wd)[t];
    float4 bv = ((const float4*)bd)[t];
    s4v o;
    o.x = (short)f2bf(xv.x * sigmoidf_(d * wv.x + bv.x));
    o.y = (short)f2bf(xv.y * sigmoidf_(d * wv.y + bv.y));
    o.z = (short)f2bf(xv.z * sigmoidf_(d * wv.z + bv.z));
    o.w = (short)f2bf(xv.w * sigmoidf_(d * wv.w + bv.w));
    ((s4v*)(xg + (size_t)row * CDIM))[t] = o;
}

// ---------------- Kernel 3: Wt[n][k] = bf16(W[k][n]) (transpose 1024x3072) -----------
__global__ void packW_kernel(const float* __restrict__ W, u16* __restrict__ Wt) {
    __shared__ float tile[64][65];
    int k0 = blockIdx.x * 64, n0 = blockIdx.y * 64;
    int tx = threadIdx.x & 63, ty = threadIdx.x >> 6;  // ty 0..3
    #pragma unroll
    for (int yy = ty; yy < 64; yy += 4)
        tile[yy][tx] = W[(size_t)(k0 + yy) * N3 + n0 + tx];
    __syncthreads();
    #pragma unroll
    for (int yy = ty; yy < 64; yy += 4)
        Wt[(size_t)(n0 + yy) * CDIM + k0 + tx] = f2bf(tile[tx][yy]);
}

// ---------------- Kernel 4: bf16 MFMA GEMM (m97-style), fused chunk epilogue --------
// qkv = xg @ W + b : M=8192, N=3072, K=1024. A=[M][K] bf16, Bt=[N][K] bf16.
// global_load_lds width=16 into XOR-swizzled LDS (swizzle applied on the global
// address side; LDS dest stays lane-contiguous). Frag reads: 2 lanes/bank (free).
// chunk 0 (qk):  sigmoid -> ksig bf16 [B,H,L,HD]
// chunk 1 (res): fp32 [B,L,C]
// chunk 2 (val): bf16 transposed -> vt [B,H,HD,L]
__global__ __launch_bounds__(256) void gemm_bf16_kernel(const u16* __restrict__ A,
                                                        const u16* __restrict__ Bt,
                                                        const float* __restrict__ bias,
                                                        u16* __restrict__ ksig,
                                                        float* __restrict__ resb,
                                                        u16* __restrict__ vt) {
    __shared__ __align__(16) u16 As[128 * 64];   // swizzled 16B slots: slot = row*8 + (seg^(row&7))
    __shared__ __align__(16) u16 Bs[128 * 64];
    int t = threadIdx.x;
    int m0 = blockIdx.y * 128, n0 = blockIdx.x * 128;
    int lane = t & 63, w = t >> 6;
    int i15 = lane & 15, quad = lane >> 4;
    int wm = w >> 1, wn = w & 1;

    f32x4 acc[4][4];
    #pragma unroll
    for (int i = 0; i < 4; ++i)
        #pragma unroll
        for (int j = 0; j < 4; ++j) acc[i][j] = (f32x4)(0.f);

    for (int k0 = 0; k0 < CDIM; k0 += 64) {
        #pragma unroll
        for (int p = 0; p < 4; ++p) {
            int sb = (w * 4 + p) * 64;           // wave-uniform slot base
            int s = sb + lane;
            int row = s >> 3;
            int seg = (s & 7) ^ (row & 7);       // global-side XOR swizzle
            const u16* ga = A + (size_t)(m0 + row) * CDIM + k0 + seg * 8;
            const u16* gb = Bt + (size_t)(n0 + row) * CDIM + k0 + seg * 8;
            __builtin_amdgcn_global_load_lds(
                (const __attribute__((address_space(1))) unsigned int*)ga,
                (__attribute__((address_space(3))) unsigned int*)&As[sb * 8], 16, 0, 0);
            __builtin_amdgcn_global_load_lds(
                (const __attribute__((address_space(1))) unsigned int*)gb,
                (__attribute__((address_space(3))) unsigned int*)&Bs[sb * 8], 16, 0, 0);
        }
        __syncthreads();
        #pragma unroll
        for (int kc = 0; kc < 2; ++kc) {
            s8v aF[4], bF[4];
            #pragma unroll
            for (int mt = 0; mt < 4; ++mt) {
                int row = wm * 64 + mt * 16 + i15;
                int slot = row * 8 + ((kc * 4 + quad) ^ (i15 & 7));
                aF[mt] = *(const s8v*)&As[slot * 8];
            }
            #pragma unroll
            for (int nt = 0; nt < 4; ++nt) {
                int row = wn * 64 + nt * 16 + i15;
                int slot = row * 8 + ((kc * 4 + quad) ^ (i15 & 7));
                bF[nt] = *(const s8v*)&Bs[slot * 8];
            }
            #pragma unroll
            for (int mt = 0; mt < 4; ++mt)
                #pragma unroll
                for (int nt = 0; nt < 4; ++nt)
                    acc[mt][nt] = __builtin_amdgcn_mfma_f32_16x16x32_bf16(aF[mt], bF[nt], acc[mt][nt], 0, 0, 0);
        }
        __syncthreads();
    }

    int chunk = n0 >> 10;
    #pragma unroll
    for (int nt = 0; nt < 4; ++nt) {
        int ncol = n0 + wn * 64 + nt * 16 + i15;
        float bv = bias[ncol];
        #pragma unroll
        for (int mt = 0; mt < 4; ++mt) {
            int mbase = m0 + wm * 64 + mt * 16 + quad * 4;
            if (chunk == 0) {
                int h = (ncol >> 7) & 7, d = ncol & 127;
                #pragma unroll
                for (int r = 0; r < 4; ++r) {
                    int mrow = mbase + r;
                    int bb = mrow >> 9, l = mrow & 511;
                    ksig[(((size_t)bb * NH + h) * LDIM + l) * HD + d] = f2bf(sigmoidf_(acc[mt][nt][r] + bv));
                }
            } else if (chunk == 1) {
                #pragma unroll
                for (int r = 0; r < 4; ++r) {
                    int mrow = mbase + r;
                    resb[(size_t)mrow * CDIM + (ncol - CDIM)] = acc[mt][nt][r] + bv;
                }
            } else {
                int h = (ncol >> 7) & 7, d = ncol & 127;
                int bb = mbase >> 9, l = mbase & 511;   // 4 consecutive l, no 512-wrap (mbase%4==0)
                s4v pk;
                pk.x = (short)f2bf(acc[mt][nt][0] + bv);
                pk.y = (short)f2bf(acc[mt][nt][1] + bv);
                pk.z = (short)f2bf(acc[mt][nt][2] + bv);
                pk.w = (short)f2bf(acc[mt][nt][3] + bv);
                *(s4v*)&vt[(((size_t)bb * NH + h) * HD + d) * LDIM + l] = pk;
            }
        }
    }
}

// ---------------- Kernel 5: fused MFMA attention ----------------
// 1D grid id = l*128 + b*8 + h  ->  id%8 == h: all l-blocks of (b,h) share an XCD
// (K/Vt head slices stay L2-resident). Per block: 64 l-rows, 4 waves x 16 rows.
// O_unnorm += P.V, rowsum += sum(P); divide once at the end (linear norm).
__global__ __launch_bounds__(256) void attn_kernel(const u16* __restrict__ ksig,
                                                   const u16* __restrict__ vt,
                                                   const float* __restrict__ resb,
                                                   const float* __restrict__ adj,
                                                   float* __restrict__ out) {
    __shared__ __align__(16) u16 lds_ks[64][136];  // K tile [m][d], pad-> 2-way (free) frag banks
    __shared__ __align__(16) u16 lds_vt[128][72];  // V^T tile [d][m], 144B rows: aligned b128 frags
    __shared__ __align__(16) u16 lds_ps[4][16][72];// per-wave P tile [l][m]
    __shared__ __align__(16) u16 lds_adj[64][68];  // 0x0000 / 0xFFFF mask, conflict-free reads

    int t = threadIdx.x;
    int lane = t & 63, w = t >> 6;
    int i15 = lane & 15, quad = lane >> 4;
    int bid = blockIdx.x;
    int l0 = (bid >> 7) * 64;
    int b  = (bid >> 3) & 15;
    int h  = bid & 7;

    const u16* ksig_bh = ksig + ((size_t)b * NH + h) * LDIM * HD;
    const u16* vt_bh   = vt + ((size_t)b * NH + h) * HD * LDIM;

    // Q A-frags from global (sigmoid pre-applied in GEMM epilogue)
    s8v aQ[4];
    {
        const u16* qrow = ksig_bh + (size_t)(l0 + w * 16 + i15) * HD + quad * 8;
        #pragma unroll
        for (int kc = 0; kc < 4; ++kc) aQ[kc] = *(const s8v*)(qrow + kc * 32);
    }

    f32x4 accO[8];
    #pragma unroll
    for (int i = 0; i < 8; ++i) accO[i] = (f32x4)(0.f);
    float prs[4] = {0.f, 0.f, 0.f, 0.f};

    const float scale = 0.08838834764831845f;  // 1/sqrt(128)

    for (int m0 = 0; m0 < LDIM; m0 += 64) {
        // --- stage K tile: 64 rows x 16 b128 ---
        #pragma unroll
        for (int p = 0; p < 4; ++p) {
            int c = t + p * 256;
            int row = c >> 4, c16 = c & 15;
            *(s8v*)&lds_ks[row][c16 * 8] =
                *(const s8v*)(ksig_bh + (size_t)(m0 + row) * HD + c16 * 8);
        }
        // --- stage V^T tile: 128 d-rows x 8 b128 (bf16 from GEMM, no transpose work) ---
        #pragma unroll
        for (int p = 0; p < 4; ++p) {
            int c = t + p * 256;
            int row = c >> 3, seg = c & 7;
            *(s8v*)&lds_vt[row][seg * 8] =
                *(const s8v*)(vt_bh + (size_t)row * LDIM + m0 + seg * 8);
        }
        // --- stage adj mask tile: 64 x 64 -> u16 0/0xFFFF, float4-coalesced ---
        #pragma unroll
        for (int p = 0; p < 4; ++p) {
            int c = t + p * 256;
            int row = c >> 4, c4 = (c & 15) * 4;
            float4 av = *(const float4*)&adj[((size_t)b * LDIM + l0 + row) * LDIM + m0 + c4];
            s4v mk;
            mk.x = (short)(av.x != 0.f ? 0xFFFF : 0);
            mk.y = (short)(av.y != 0.f ? 0xFFFF : 0);
            mk.z = (short)(av.z != 0.f ? 0xFFFF : 0);
            mk.w = (short)(av.w != 0.f ? 0xFFFF : 0);
            *(s4v*)&lds_adj[row][c4] = mk;
        }
        __syncthreads();

        // --- S = sig(Q) sig(K)^T : 4 key-tiles x 4 k-steps ---
        f32x4 S[4];
        #pragma unroll
        for (int nt = 0; nt < 4; ++nt) {
            S[nt] = (f32x4)(0.f);
            #pragma unroll
            for (int kc = 0; kc < 4; ++kc) {
                s8v bK = *(const s8v*)&lds_ks[nt * 16 + i15][kc * 32 + quad * 8];
                S[nt] = __builtin_amdgcn_mfma_f32_16x16x32_bf16(aQ[kc], bK, S[nt], 0, 0, 0);
            }
        }

        // --- mask (bitwise AND with 0/0xFFFFFFFF), rowsum, P -> LDS (per-wave) ---
        #pragma unroll
        for (int nt = 0; nt < 4; ++nt) {
            #pragma unroll
            for (int r = 0; r < 4; ++r) {
                int am = *(const short*)&lds_adj[w * 16 + quad * 4 + r][nt * 16 + i15]; // sext
                float p = andmaskf_(S[nt][r] * scale, am);
                prs[r] += p;
                lds_ps[w][quad * 4 + r][nt * 16 + i15] = f2bf(p);
            }
        }

        // --- O += P . V ---
        {
            s8v aP[2];
            #pragma unroll
            for (int ks = 0; ks < 2; ++ks)
                aP[ks] = *(const s8v*)&lds_ps[w][i15][ks * 32 + quad * 8];
            #pragma unroll
            for (int ntd = 0; ntd < 8; ++ntd) {
                #pragma unroll
                for (int ks = 0; ks < 2; ++ks) {
                    s8v bV = *(const s8v*)&lds_vt[ntd * 16 + i15][ks * 32 + quad * 8];
                    accO[ntd] = __builtin_amdgcn_mfma_f32_16x16x32_bf16(aP[ks], bV, accO[ntd], 0, 0, 0);
                }
            }
        }
        __syncthreads();
    }

    // --- epilogue: reduce rowsums across the 16 key-lanes, normalize, +res, relu ---
    float inv[4];
    #pragma unroll
    for (int r = 0; r < 4; ++r) {
        float s = prs[r];
        s += __shfl_xor(s, 1);
        s += __shfl_xor(s, 2);
        s += __shfl_xor(s, 4);
        s += __shfl_xor(s, 8);
        inv[r] = 1.0f / (s + 1e-6f);
    }
    #pragma unroll
    for (int ntd = 0; ntd < 8; ++ntd) {
        int dcol = h * HD + ntd * 16 + i15;
        #pragma unroll
        for (int r = 0; r < 4; ++r) {
            size_t idx = ((size_t)b * LDIM + l0 + w * 16 + quad * 4 + r) * CDIM + dcol;
            float v = accO[ntd][r] * inv[r] + resb[idx];
            out[idx] = fmaxf(v, 0.f);
        }
    }
}

// ---------------- launch ----------------
extern "C" void kernel_launch(void* const* d_in, const int* in_sizes, int n_in,
                              void* d_out, int out_size, void* d_ws, size_t ws_size,
                              hipStream_t stream) {
    (void)in_sizes; (void)n_in; (void)out_size; (void)ws_size;
    const float* x     = (const float*)d_in[0];
    const float* adj   = (const float*)d_in[1];
    const float* W_qkv = (const float*)d_in[2];
    const float* b_qkv = (const float*)d_in[3];
    const float* W_d   = (const float*)d_in[4];
    const float* b_d   = (const float*)d_in[5];
    float* out = (float*)d_out;

    char* ws = (char*)d_ws;
    size_t off = 0;
    float* deg  = (float*)(ws + off); off += 32768;                       // 8192 f32
    u16*   xg   = (u16*)(ws + off);   off += (size_t)MROWS * CDIM * 2;    // 16 MB
    u16*   Wt   = (u16*)(ws + off);   off += (size_t)N3 * CDIM * 2;       // 6 MB
    u16*   ksig = (u16*)(ws + off);   off += (size_t)MROWS * CDIM * 2;    // 16 MB
    float* resb = (float*)(ws + off); off += (size_t)MROWS * CDIM * 4;    // 32 MB
    u16*   vt   = (u16*)(ws + off);   off += (size_t)MROWS * CDIM * 2;    // 16 MB

    degree_kernel<<<MROWS, 64, 0, stream>>>(adj, deg);
    gate_kernel<<<MROWS, 256, 0, stream>>>(x, deg, W_d, b_d, xg);
    packW_kernel<<<dim3(CDIM / 64, N3 / 64), 256, 0, stream>>>(W_qkv, Wt);
    gemm_bf16_kernel<<<dim3(N3 / 128, MROWS / 128), 256, 0, stream>>>(xg, Wt, b_qkv, ksig, resb, vt);
    attn_kernel<<<LDIM / 64 * NH * BDIM, 256, 0, stream>>>(ksig, vt, resb, adj, out);
}

// Round 4
// 210.867 us; speedup vs baseline: 6.4720x; 1.3151x over previous
//
#include <hip/hip_runtime.h>
#include <math.h>

#define BDIM 16
#define LDIM 512
#define CDIM 1024
#define NH 8
#define HD 128
#define MROWS (BDIM * LDIM)   /* 8192 */
#define N3 (3 * CDIM)         /* 3072 */

typedef unsigned short u16;
typedef unsigned long long u64;
typedef short s8v __attribute__((ext_vector_type(8)));   // 8 bf16 = 4 VGPRs (MFMA A/B frag)
typedef short s4v __attribute__((ext_vector_type(4)));   // 4 bf16 = 2 VGPRs
typedef float f32x4 __attribute__((ext_vector_type(4))); // MFMA C/D frag

__device__ __forceinline__ float sigmoidf_(float z) {
    return 1.0f / (1.0f + __expf(-z));
}
__device__ __forceinline__ u16 f2bf(float f) {
    union { float f; unsigned int u; } v; v.f = f;
    unsigned int u = v.u;
    unsigned int r = (u + 0x7FFFu + ((u >> 16) & 1u)) >> 16;   // round-nearest-even
    return (u16)r;
}
__device__ __forceinline__ float bf2f(u16 b) {
    union { unsigned int u; float f; } v; v.u = ((unsigned int)b) << 16;
    return v.f;
}

// ---------------- Kernel 1: degree = adj.sum(-1)  +  adj bitmask pack ----------------
__global__ void degree_kernel(const float* __restrict__ adj, float* __restrict__ deg,
                              u64* __restrict__ adjbits) {
    int row = blockIdx.x;            // 0..B*L-1
    int lane = threadIdx.x;          // 0..63
    const float* a = adj + (size_t)row * LDIM;
    float s = 0.f;
    #pragma unroll
    for (int mc = 0; mc < LDIM; mc += 64) {
        float v = a[mc + lane];
        s += v;
        u64 m = __ballot(v != 0.f);
        if (lane == 0) adjbits[(size_t)row * (LDIM / 64) + (mc >> 6)] = m;
    }
    #pragma unroll
    for (int off = 32; off > 0; off >>= 1) s += __shfl_down(s, off);
    if (lane == 0) deg[row] = s;
}

// ---------------- Kernel 2: xg = bf16( x * sigmoid(deg*W_d + b_d) ) ----------------
__global__ void gate_kernel(const float* __restrict__ x, const float* __restrict__ deg,
                            const float* __restrict__ Wd, const float* __restrict__ bd,
                            u16* __restrict__ xg) {
    int row = blockIdx.x;
    int t = threadIdx.x;
    float d = deg[row];
    float4 xv = ((const float4*)(x + (size_t)row * CDIM))[t];
    float4 wv = ((const float4*)Wd)[t];
    float4 bv = ((const float4*)bd)[t];
    s4v o;
    o.x = (short)f2bf(xv.x * sigmoidf_(d * wv.x + bv.x));
    o.y = (short)f2bf(xv.y * sigmoidf_(d * wv.y + bv.y));
    o.z = (short)f2bf(xv.z * sigmoidf_(d * wv.z + bv.z));
    o.w = (short)f2bf(xv.w * sigmoidf_(d * wv.w + bv.w));
    ((s4v*)(xg + (size_t)row * CDIM))[t] = o;
}

// ---------------- Kernel 3: Wt[n][k] = bf16(W[k][n]) (transpose 1024x3072) -----------
__global__ void packW_kernel(const float* __restrict__ W, u16* __restrict__ Wt) {
    __shared__ float tile[64][65];
    int k0 = blockIdx.x * 64, n0 = blockIdx.y * 64;
    int tx = threadIdx.x & 63, ty = threadIdx.x >> 6;  // ty 0..3
    #pragma unroll
    for (int yy = ty; yy < 64; yy += 4)
        tile[yy][tx] = W[(size_t)(k0 + yy) * N3 + n0 + tx];
    __syncthreads();
    #pragma unroll
    for (int yy = ty; yy < 64; yy += 4)
        Wt[(size_t)(n0 + yy) * CDIM + k0 + tx] = f2bf(tile[tx][yy]);
}

// ---------------- Kernel 4: bf16 MFMA GEMM (m97-style), fused chunk epilogue --------
// qkv = xg @ W + b : M=8192, N=3072, K=1024. A=[M][K] bf16, Bt=[N][K] bf16.
// global_load_lds width=16 into XOR-swizzled LDS (swizzle applied on the global
// address side; LDS dest stays lane-contiguous). Frag reads: 2 lanes/bank (free).
// chunk 0 (qk):  sigmoid -> ksig bf16 [B,H,L,HD]
// chunk 1 (res): bf16 [B,L,C]
// chunk 2 (val): bf16 transposed -> vt [B,H,HD,L]
// __launch_bounds__(256,3): cap combined VGPR+AGPR at ~170 -> 3 blocks/CU.
__global__ __launch_bounds__(256, 3) void gemm_bf16_kernel(const u16* __restrict__ A,
                                                           const u16* __restrict__ Bt,
                                                           const float* __restrict__ bias,
                                                           u16* __restrict__ ksig,
                                                           u16* __restrict__ resb,
                                                           u16* __restrict__ vt) {
    __shared__ __align__(16) u16 As[128 * 64];   // swizzled 16B slots: slot = row*8 + (seg^(row&7))
    __shared__ __align__(16) u16 Bs[128 * 64];
    int t = threadIdx.x;
    int m0 = blockIdx.y * 128, n0 = blockIdx.x * 128;
    int lane = t & 63, w = t >> 6;
    int i15 = lane & 15, quad = lane >> 4;
    int wm = w >> 1, wn = w & 1;

    f32x4 acc[4][4];
    #pragma unroll
    for (int i = 0; i < 4; ++i)
        #pragma unroll
        for (int j = 0; j < 4; ++j) acc[i][j] = (f32x4)(0.f);

    for (int k0 = 0; k0 < CDIM; k0 += 64) {
        #pragma unroll
        for (int p = 0; p < 4; ++p) {
            int sb = (w * 4 + p) * 64;           // wave-uniform slot base
            int s = sb + lane;
            int row = s >> 3;
            int seg = (s & 7) ^ (row & 7);       // global-side XOR swizzle
            const u16* ga = A + (size_t)(m0 + row) * CDIM + k0 + seg * 8;
            const u16* gb = Bt + (size_t)(n0 + row) * CDIM + k0 + seg * 8;
            __builtin_amdgcn_global_load_lds(
                (const __attribute__((address_space(1))) unsigned int*)ga,
                (__attribute__((address_space(3))) unsigned int*)&As[sb * 8], 16, 0, 0);
            __builtin_amdgcn_global_load_lds(
                (const __attribute__((address_space(1))) unsigned int*)gb,
                (__attribute__((address_space(3))) unsigned int*)&Bs[sb * 8], 16, 0, 0);
        }
        __syncthreads();
        #pragma unroll
        for (int kc = 0; kc < 2; ++kc) {
            s8v aF[4], bF[4];
            #pragma unroll
            for (int mt = 0; mt < 4; ++mt) {
                int row = wm * 64 + mt * 16 + i15;
                int slot = row * 8 + ((kc * 4 + quad) ^ (i15 & 7));
                aF[mt] = *(const s8v*)&As[slot * 8];
            }
            #pragma unroll
            for (int nt = 0; nt < 4; ++nt) {
                int row = wn * 64 + nt * 16 + i15;
                int slot = row * 8 + ((kc * 4 + quad) ^ (i15 & 7));
                bF[nt] = *(const s8v*)&Bs[slot * 8];
            }
            #pragma unroll
            for (int mt = 0; mt < 4; ++mt)
                #pragma unroll
                for (int nt = 0; nt < 4; ++nt)
                    acc[mt][nt] = __builtin_amdgcn_mfma_f32_16x16x32_bf16(aF[mt], bF[nt], acc[mt][nt], 0, 0, 0);
        }
        __syncthreads();
    }

    int chunk = n0 >> 10;
    #pragma unroll
    for (int nt = 0; nt < 4; ++nt) {
        int ncol = n0 + wn * 64 + nt * 16 + i15;
        float bv = bias[ncol];
        #pragma unroll
        for (int mt = 0; mt < 4; ++mt) {
            int mbase = m0 + wm * 64 + mt * 16 + quad * 4;
            if (chunk == 0) {
                int h = (ncol >> 7) & 7, d = ncol & 127;
                #pragma unroll
                for (int r = 0; r < 4; ++r) {
                    int mrow = mbase + r;
                    int bb = mrow >> 9, l = mrow & 511;
                    ksig[(((size_t)bb * NH + h) * LDIM + l) * HD + d] = f2bf(sigmoidf_(acc[mt][nt][r] + bv));
                }
            } else if (chunk == 1) {
                #pragma unroll
                for (int r = 0; r < 4; ++r) {
                    int mrow = mbase + r;
                    resb[(size_t)mrow * CDIM + (ncol - CDIM)] = f2bf(acc[mt][nt][r] + bv);
                }
            } else {
                int h = (ncol >> 7) & 7, d = ncol & 127;
                int bb = mbase >> 9, l = mbase & 511;   // 4 consecutive l, no 512-wrap (mbase%4==0)
                s4v pk;
                pk.x = (short)f2bf(acc[mt][nt][0] + bv);
                pk.y = (short)f2bf(acc[mt][nt][1] + bv);
                pk.z = (short)f2bf(acc[mt][nt][2] + bv);
                pk.w = (short)f2bf(acc[mt][nt][3] + bv);
                *(s4v*)&vt[(((size_t)bb * NH + h) * HD + d) * LDIM + l] = pk;
            }
        }
    }
}

// ---------------- Kernel 5: fused MFMA attention ----------------
// 1D grid id = l*128 + b*8 + h  ->  id%8 == h: all l-blocks of (b,h) share an XCD
// (K/Vt head slices stay L2-resident). Per block: 64 l-rows, 4 waves x 16 rows.
// K/Vt staged via global_load_lds with XOR swizzle; adj applied from bitmask words.
// O_unnorm += P.V, rowsum += sum(P); divide once at the end (linear norm).
__global__ __launch_bounds__(256) void attn_kernel(const u16* __restrict__ ksig,
                                                   const u16* __restrict__ vt,
                                                   const u16* __restrict__ resb,
                                                   const u64* __restrict__ adjbits,
                                                   float* __restrict__ out) {
    __shared__ __align__(16) u16 lds_ks[64 * 128];  // swizzled: slot = row*16 + (seg^(row&15))
    __shared__ __align__(16) u16 lds_vt[128 * 64];  // swizzled: slot = row*8 + (seg^(row&7))
    __shared__ __align__(16) u16 lds_ps[4][16][72]; // per-wave P tile [l][m], 64 + 8 pad

    int t = threadIdx.x;
    int lane = t & 63, w = t >> 6;
    int i15 = lane & 15, quad = lane >> 4;
    int bid = blockIdx.x;
    int l0 = (bid >> 7) * 64;
    int b  = (bid >> 3) & 15;
    int h  = bid & 7;

    const u16* ksig_bh = ksig + ((size_t)b * NH + h) * LDIM * HD;
    const u16* vt_bh   = vt + ((size_t)b * NH + h) * HD * LDIM;
    const u64* abits   = adjbits + ((size_t)b * LDIM + l0 + w * 16 + quad * 4) * (LDIM / 64);

    // Q A-frags from global (sigmoid pre-applied in GEMM epilogue)
    s8v aQ[4];
    {
        const u16* qrow = ksig_bh + (size_t)(l0 + w * 16 + i15) * HD + quad * 8;
        #pragma unroll
        for (int kc = 0; kc < 4; ++kc) aQ[kc] = *(const s8v*)(qrow + kc * 32);
    }

    f32x4 accO[8];
    #pragma unroll
    for (int i = 0; i < 8; ++i) accO[i] = (f32x4)(0.f);
    float prs[4] = {0.f, 0.f, 0.f, 0.f};

    const float scale = 0.08838834764831845f;  // 1/sqrt(128)

    for (int m0 = 0; m0 < LDIM; m0 += 64) {
        // --- stage K tile via DMA: 64 rows x 16 segs, 4 insts/thread ---
        #pragma unroll
        for (int p = 0; p < 4; ++p) {
            int sb = (w * 4 + p) * 64;
            int s = sb + lane;
            int row = s >> 4;
            int seg = (s & 15) ^ (row & 15);
            const u16* g = ksig_bh + (size_t)(m0 + row) * HD + seg * 8;
            __builtin_amdgcn_global_load_lds(
                (const __attribute__((address_space(1))) unsigned int*)g,
                (__attribute__((address_space(3))) unsigned int*)&lds_ks[sb * 8], 16, 0, 0);
        }
        // --- stage V^T tile via DMA: 128 rows x 8 segs, 4 insts/thread ---
        #pragma unroll
        for (int p = 0; p < 4; ++p) {
            int sb = (w * 4 + p) * 64;
            int s = sb + lane;
            int row = s >> 3;
            int seg = (s & 7) ^ (row & 7);
            const u16* g = vt_bh + (size_t)row * LDIM + m0 + seg * 8;
            __builtin_amdgcn_global_load_lds(
                (const __attribute__((address_space(1))) unsigned int*)g,
                (__attribute__((address_space(3))) unsigned int*)&lds_vt[sb * 8], 16, 0, 0);
        }
        // --- adj mask words for this m-chunk (broadcast loads, hide under DMA) ---
        unsigned int mw0[4], mw1[4];
        #pragma unroll
        for (int r = 0; r < 4; ++r) {
            u64 wrd = abits[(size_t)r * (LDIM / 64) + (m0 >> 6)];
            mw0[r] = (unsigned int)wrd;
            mw1[r] = (unsigned int)(wrd >> 32);
        }
        __syncthreads();

        // --- S = sig(Q) sig(K)^T : 4 key-tiles x 4 k-steps ---
        f32x4 S[4];
        #pragma unroll
        for (int nt = 0; nt < 4; ++nt) {
            S[nt] = (f32x4)(0.f);
            #pragma unroll
            for (int kc = 0; kc < 4; ++kc) {
                int row = nt * 16 + i15;
                int slot = row * 16 + ((kc * 4 + quad) ^ (row & 15));
                s8v bK = *(const s8v*)&lds_ks[slot * 8];
                S[nt] = __builtin_amdgcn_mfma_f32_16x16x32_bf16(aQ[kc], bK, S[nt], 0, 0, 0);
            }
        }

        // --- mask via bit-test, rowsum, P -> LDS (per-wave, no barrier) ---
        #pragma unroll
        for (int nt = 0; nt < 4; ++nt) {
            int sh = (nt & 1) * 16 + i15;
            #pragma unroll
            for (int r = 0; r < 4; ++r) {
                unsigned int half = (nt < 2) ? mw0[r] : mw1[r];
                float p = ((half >> sh) & 1u) ? S[nt][r] * scale : 0.f;
                prs[r] += p;
                lds_ps[w][quad * 4 + r][nt * 16 + i15] = f2bf(p);
            }
        }

        // --- O += P . V ---
        {
            s8v aP[2];
            #pragma unroll
            for (int ks = 0; ks < 2; ++ks)
                aP[ks] = *(const s8v*)&lds_ps[w][i15][ks * 32 + quad * 8];
            #pragma unroll
            for (int ntd = 0; ntd < 8; ++ntd) {
                #pragma unroll
                for (int ks = 0; ks < 2; ++ks) {
                    int row = ntd * 16 + i15;
                    int slot = row * 8 + ((ks * 4 + quad) ^ (row & 7));
                    s8v bV = *(const s8v*)&lds_vt[slot * 8];
                    accO[ntd] = __builtin_amdgcn_mfma_f32_16x16x32_bf16(aP[ks], bV, accO[ntd], 0, 0, 0);
                }
            }
        }
        __syncthreads();
    }

    // --- epilogue: reduce rowsums across the 16 key-lanes, normalize, +res, relu ---
    float inv[4];
    #pragma unroll
    for (int r = 0; r < 4; ++r) {
        float s = prs[r];
        s += __shfl_xor(s, 1);
        s += __shfl_xor(s, 2);
        s += __shfl_xor(s, 4);
        s += __shfl_xor(s, 8);
        inv[r] = 1.0f / (s + 1e-6f);
    }
    #pragma unroll
    for (int ntd = 0; ntd < 8; ++ntd) {
        int dcol = h * HD + ntd * 16 + i15;
        #pragma unroll
        for (int r = 0; r < 4; ++r) {
            size_t idx = ((size_t)b * LDIM + l0 + w * 16 + quad * 4 + r) * CDIM + dcol;
            float v = accO[ntd][r] * inv[r] + bf2f(resb[idx]);
            out[idx] = fmaxf(v, 0.f);
        }
    }
}

// ---------------- launch ----------------
extern "C" void kernel_launch(void* const* d_in, const int* in_sizes, int n_in,
                              void* d_out, int out_size, void* d_ws, size_t ws_size,
                              hipStream_t stream) {
    (void)in_sizes; (void)n_in; (void)out_size; (void)ws_size;
    const float* x     = (const float*)d_in[0];
    const float* adj   = (const float*)d_in[1];
    const float* W_qkv = (const float*)d_in[2];
    const float* b_qkv = (const float*)d_in[3];
    const float* W_d   = (const float*)d_in[4];
    const float* b_d   = (const float*)d_in[5];
    float* out = (float*)d_out;

    char* ws = (char*)d_ws;
    size_t off = 0;
    float* deg  = (float*)(ws + off); off += 32768;                       // 8192 f32
    u64* adjb   = (u64*)(ws + off);   off += (size_t)MROWS * 8 * 8;       // 512 KB
    u16*   xg   = (u16*)(ws + off);   off += (size_t)MROWS * CDIM * 2;    // 16 MB
    u16*   Wt   = (u16*)(ws + off);   off += (size_t)N3 * CDIM * 2;       // 6 MB
    u16*   ksig = (u16*)(ws + off);   off += (size_t)MROWS * CDIM * 2;    // 16 MB
    u16*   resb = (u16*)(ws + off);   off += (size_t)MROWS * CDIM * 2;    // 16 MB
    u16*   vt   = (u16*)(ws + off);   off += (size_t)MROWS * CDIM * 2;    // 16 MB

    degree_kernel<<<MROWS, 64, 0, stream>>>(adj, deg, adjb);
    gate_kernel<<<MROWS, 256, 0, stream>>>(x, deg, W_d, b_d, xg);
    packW_kernel<<<dim3(CDIM / 64, N3 / 64), 256, 0, stream>>>(W_qkv, Wt);
    gemm_bf16_kernel<<<dim3(N3 / 128, MROWS / 128), 256, 0, stream>>>(xg, Wt, b_qkv, ksig, resb, vt);
    attn_kernel<<<LDIM / 64 * NH * BDIM, 256, 0, stream>>>(ksig, vt, resb, adjb, out);
}